// Round 9
// baseline (113.235 us; speedup 1.0000x reference)
//
#include <hip/hip_runtime.h>
#include <hip/hip_fp16.h>
#include <stdint.h>

#define HH 224
#define HWD 224
#define HWP (HH*HWD)      // 50176
#define PH 112
#define PW 112
#define PHW (PH*PW)       // 12544
#define FCK 200704
#define KSEG 196

typedef _Float16 f16x8 __attribute__((ext_vector_type(8)));
typedef float f32x4 __attribute__((ext_vector_type(4)));
typedef float f32x4v __attribute__((ext_vector_type(4)));
typedef uint32_t u32x4v __attribute__((ext_vector_type(4)));

static __device__ __forceinline__ uint32_t pkh2(float a, float b) {
  __half2 h = __floats2half2_rn(a, b);
  return __builtin_bit_cast(uint32_t, h);
}
static __device__ __forceinline__ f32x4 mfma16(uint4 a, uint4 b, f32x4 c) {
  return __builtin_amdgcn_mfma_f32_16x16x32_f16(
      __builtin_bit_cast(f16x8, a), __builtin_bit_cast(f16x8, b), c, 0, 0, 0);
}
// non-temporal loads (LRU streaming hint; still snoops L2 -> coherent)
static __device__ __forceinline__ uint4 ntld_u4(const void* p) {
  u32x4v v = __builtin_nontemporal_load((const u32x4v*)p);
  return (uint4){v.x, v.y, v.z, v.w};
}
static __device__ __forceinline__ float4 ntld_f4(const void* p) {
  f32x4v v = __builtin_nontemporal_load((const f32x4v*)p);
  return make_float4(v.x, v.y, v.z, v.w);
}

// ======== MFMA conv template (validated R4-R8) ========
// A (M=16 px along x, K=32 = 2 taps x 16 c): lane l -> px r=l&15, tap parity l>>5,
//   c = ((l>>4)&1)*8 + e.  B: lane l -> o=l&15, same K map.  C/D: o=l&15, px=(l>>4)*4+reg.
// Mask m_j[px,tap] uniform over lane's 8 A elems -> AND-mask on A fragment.
// R9: double-buffered ts/dt (2 barriers/tile, was 3); nt loads on stream-once
// data to preserve L2 residency of h1t/pooled/partial.

// ---------------- conv1 (+fused sel): 3->16 via MFMA ----------------
__global__ __launch_bounds__(256, 3) void conv1_kernel(
    const float* __restrict__ x, const float* __restrict__ depth,
    const float* __restrict__ fxp,
    const float* __restrict__ w0, const float* __restrict__ w1,
    const float* __restrict__ w2, const float* __restrict__ bias,
    uint32_t* __restrict__ sel, __half* __restrict__ h1t) {
  __shared__ __align__(16) __half ts[2][324*24]; // 31104 B dbuf tile
  __shared__ __align__(16) uint4 wlds[15*64];    // 15360 B B-frags
  __shared__ float dt[2][324];                   //  2592 B depth tile dbuf
  __shared__ uint32_t sbits[256];                //  1024 B
  __shared__ __align__(16) __half hbuf[1024];    //  2048 B epilogue bounce
  int tid = threadIdx.x;
  int lane = tid & 63, wid = tid >> 6;
  int r = lane & 15;
  int tapPar = lane >> 5;
  int c0 = ((lane >> 4) & 1) * 8;
  float bo = bias[r];
  float fx = fxp[0];

  // ---- stage B-frags once into LDS (branchless clamped loads) ----
  #pragma unroll
  for (int it = 0; it < 4; ++it) {
    int t = tid + it*256;
    int tc = min(t, 959);
    int ln = tc & 63; int pj = tc >> 6;
    int p = pj / 3, j = pj % 3;
    int o = ln & 15; int tap = p*2 + (ln >> 5);
    int cbase = ((ln >> 4) & 1) * 8;
    const float* wj = (j == 0) ? w0 : (j == 1) ? w1 : w2;
    float f[8];
    #pragma unroll
    for (int e = 0; e < 8; ++e) {
      int c = cbase + e;
      float v = wj[o*27 + min(c,2)*9 + min(tap,8)];
      f[e] = (tap <= 8 && c < 3) ? v : 0.f;
    }
    if (t < 960) {
      uint4 wv = { pkh2(f[0],f[1]), pkh2(f[2],f[3]), pkh2(f[4],f[5]), pkh2(f[6],f[7]) };
      wlds[pj*64 + ln] = wv;
    }
  }

  // ---- prefetch tile 0 (x + depth), nt ----
  int tbase = blockIdx.x * 4;
  float pf[2][3]; float pd[2];
  {
    int tile = tbase;
    int n = tile/196, rem = tile%196, br = rem/14, bc = rem%14;
    int y0 = br*16 - 1, x0 = bc*16 - 1;
    const float* xn = x + (size_t)n*3*HWP;
    const float* dn = depth + (size_t)n*HWP;
    #pragma unroll
    for (int it = 0; it < 2; ++it) {
      int p = min(tid + it*256, 323);
      int yy = y0 + p/18, xx = x0 + p%18;
      int gy = min(max(yy,0),HH-1), gx = min(max(xx,0),HWD-1);
      size_t off = (size_t)gy*HWD + gx;
      pf[it][0] = __builtin_nontemporal_load(xn + off);
      pf[it][1] = __builtin_nontemporal_load(xn + HWP + off);
      pf[it][2] = __builtin_nontemporal_load(xn + 2*HWP + off);
      float dv = __builtin_nontemporal_load(dn + off);
      pd[it] = (yy>=0 && yy<HH && xx>=0 && xx<HWD) ? dv : 0.f;  // true 0-pad
    }
  }

  for (int ti = 0; ti < 4; ++ti) {
    int cur = ti & 1;
    int tile = tbase + ti;
    int n = tile/196, rem = tile%196, br = rem/14, bc = rem%14;
    // ---- ds_write current tile into buf[cur] ----
    #pragma unroll
    for (int it = 0; it < 2; ++it) {
      int p = tid + it*256;
      if (p < 324) {
        uint4 v0 = { pkh2(pf[it][0], pf[it][1]), pkh2(pf[it][2], 0.f), 0u, 0u };
        uint4 z  = { 0u, 0u, 0u, 0u };
        *(uint4*)(&ts[cur][0] + p*24)      = v0;
        *(uint4*)(&ts[cur][0] + p*24 + 8)  = z;
        *(uint4*)(&ts[cur][0] + p*24 + 16) = z;
        dt[cur][p] = pd[it];
      }
    }
    // ---- issue next tile's global loads (nt) ----
    if (ti < 3) {
      int tile2 = tile + 1;
      int n2 = tile2/196, rem2 = tile2%196, br2 = rem2/14, bc2 = rem2%14;
      int y0 = br2*16 - 1, x0 = bc2*16 - 1;
      const float* xn = x + (size_t)n2*3*HWP;
      const float* dn = depth + (size_t)n2*HWP;
      #pragma unroll
      for (int it = 0; it < 2; ++it) {
        int p = min(tid + it*256, 323);
        int yy = y0 + p/18, xx = x0 + p%18;
        int gy = min(max(yy,0),HH-1), gx = min(max(xx,0),HWD-1);
        size_t off = (size_t)gy*HWD + gx;
        pf[it][0] = __builtin_nontemporal_load(xn + off);
        pf[it][1] = __builtin_nontemporal_load(xn + HWP + off);
        pf[it][2] = __builtin_nontemporal_load(xn + 2*HWP + off);
        float dv = __builtin_nontemporal_load(dn + off);
        pd[it] = (yy>=0 && yy<HH && xx>=0 && xx<HWD) ? dv : 0.f;
      }
    }
    __syncthreads();                                 // bar_A: buf[cur] ready
    // ---- sel bits (math == validated sel_kernel) ----
    {
      int py = tid >> 4, px = tid & 15;
      float c = dt[cur][(py+1)*18 + (px+1)];
      float gr = c / fx;
      float hf = gr * 0.5f;
      uint32_t bits = 0;
      #pragma unroll
      for (int i = 0; i < 3; ++i)
        #pragma unroll
        for (int j = 0; j < 3; ++j) {
          float d = dt[cur][(py+i)*18 + (px+j)];
          int k = i*3 + j;
          uint32_t bb = 0;
          if (fabsf(d - (c + gr)) <= hf) bb |= 1u;
          if (fabsf(d - c) < hf)         bb |= 2u;
          if (fabsf(d - (c - gr)) <= hf) bb |= 4u;
          bits |= bb << (3*k);
        }
      sbits[tid] = bits;
      sel[(size_t)n*HWP + (br*16 + py)*HWD + bc*16 + px] = bits;  // for conv2
    }
    __syncthreads();                                 // bar_B: sbits ready
    uint32_t svc[4];
    #pragma unroll
    for (int ty = 0; ty < 4; ++ty) svc[ty] = sbits[(wid*4 + ty)*16 + r];
    // ---- MFMA phase (reads ts[cur]) ----
    f32x4 acc[4] = {{0,0,0,0},{0,0,0,0},{0,0,0,0},{0,0,0,0}};
    #pragma unroll
    for (int p = 0; p < 5; ++p) {
      int ta = 2*p, tb = (2*p+1 > 8) ? 8 : 2*p+1;   // tap9 dups tap8 (B=0 kills it)
      int dyL = tapPar ? tb/3 : ta/3;
      int dxL = tapPar ? tb%3 : ta%3;
      int shL = 3*(tapPar ? 2*p+1 : 2*p);
      uint4 a[4];
      #pragma unroll
      for (int ty = 0; ty < 4; ++ty) {
        int ly = wid*4 + ty;
        a[ty] = *(const uint4*)(&ts[cur][0] + ((ly + dyL)*18 + (r + dxL))*24 + c0);
      }
      #pragma unroll
      for (int j = 0; j < 3; ++j) {
        uint4 bf = wlds[(p*3 + j)*64 + lane];
        #pragma unroll
        for (int ty = 0; ty < 4; ++ty) {
          uint32_t msk = 0u - ((svc[ty] >> (shL + j)) & 1u);
          uint4 am = { a[ty].x & msk, a[ty].y & msk, a[ty].z & msk, a[ty].w & msk };
          acc[ty] = mfma16(am, bf, acc[ty]);
        }
      }
    }
    // ---- epilogue: relu + channel-last f16 store (hbuf wave-private) ----
    #pragma unroll
    for (int ty = 0; ty < 4; ++ty) {
      int gy = br*16 + wid*4 + ty;
      #pragma unroll
      for (int e = 0; e < 4; ++e) {
        float v = fmaxf(acc[ty][e] + bo, 0.f);
        hbuf[wid*256 + ((lane>>4)*4 + e)*16 + r] = __float2half(v);
      }
      uint2 hw = *(uint2*)&hbuf[wid*256 + lane*4];
      *(uint2*)(h1t + ((size_t)(n*HWP + gy*HWD) + bc*16)*16 + lane*4) = hw;
    }
    // next iter's writes go to buf[cur^1]; bar_A of next iter orders sbits reuse
  }
}

// ---------------- conv2: 16->16 via MFMA + ReLU + 2x2 maxpool -> pooled f16 CF ----------------
__global__ __launch_bounds__(256, 3) void conv2_kernel(
    const __half* __restrict__ h1t, const uint32_t* __restrict__ sel,
    const float* __restrict__ w0, const float* __restrict__ w1,
    const float* __restrict__ w2, const float* __restrict__ bias,
    __half* __restrict__ pooled) {
  __shared__ __align__(16) __half ts[2][324*24]; // 31104 B dbuf
  __shared__ __align__(16) uint4 wlds[15*64];    // 15360 B
  __shared__ float pl[64*17];                    //  4352 B
  int tid = threadIdx.x;
  int lane = tid & 63, wid = tid >> 6;
  int r = lane & 15;
  int tapPar = lane >> 5;
  int c0 = ((lane >> 4) & 1) * 8;
  float bo = bias[r];

  // ---- stage B-frags once into LDS ----
  #pragma unroll
  for (int it = 0; it < 4; ++it) {
    int t = tid + it*256;
    int tc = min(t, 959);
    int ln = tc & 63; int pj = tc >> 6;
    int p = pj / 3, j = pj % 3;
    int o = ln & 15; int tap = p*2 + (ln >> 5);
    int cbase = ((ln >> 4) & 1) * 8;
    const float* wj = (j == 0) ? w0 : (j == 1) ? w1 : w2;
    const float* wp = wj + o*144 + cbase*9 + tap;   // [o][c][k]; tap=9 stays in-bounds
    float f[8];
    #pragma unroll
    for (int e = 0; e < 8; ++e) {
      float v = wp[e*9];
      f[e] = (tap <= 8) ? v : 0.f;
    }
    if (t < 960) {
      uint4 wv = { pkh2(f[0],f[1]), pkh2(f[2],f[3]), pkh2(f[4],f[5]), pkh2(f[6],f[7]) };
      wlds[pj*64 + ln] = wv;
    }
  }

  // ---- prefetch tile 0 (nt) ----
  int tbase = blockIdx.x * 4;
  uint4 st[3]; uint32_t sv[4];
  {
    int tile = tbase;
    int n = tile/196, rem = tile%196, br = rem/14, bc = rem%14;
    int y0 = br*16 - 1, x0 = bc*16 - 1;
    const __half* hn = h1t + (size_t)n*HWP*16;
    #pragma unroll
    for (int it = 0; it < 3; ++it) {
      int w = min(tid + it*256, 647);
      int p = w >> 1, hh = w & 1;
      int gy = min(max(y0 + p/18, 0), HH-1);
      int gx = min(max(x0 + p%18, 0), HWD-1);
      st[it] = ntld_u4(hn + ((size_t)(gy*HWD + gx))*16 + hh*8);
    }
    #pragma unroll
    for (int ty = 0; ty < 4; ++ty)
      sv[ty] = __builtin_nontemporal_load(
          sel + (size_t)n*HWP + (br*16 + wid*4 + ty)*HWD + bc*16 + r);
  }

  for (int ti = 0; ti < 4; ++ti) {
    int cur = ti & 1;
    int tile = tbase + ti;
    int n = tile/196, rem = tile%196, br = rem/14, bc = rem%14;
    // ---- ds_write current tile into buf[cur] ----
    #pragma unroll
    for (int it = 0; it < 3; ++it) {
      int w = tid + it*256;
      if (w < 648) {
        int p = w >> 1, hh = w & 1;
        *(uint4*)(&ts[cur][0] + p*24 + hh*8) = st[it];
      }
    }
    uint32_t svc[4];
    #pragma unroll
    for (int ty = 0; ty < 4; ++ty) svc[ty] = sv[ty];
    // ---- issue next tile's loads (nt) ----
    if (ti < 3) {
      int tile2 = tile + 1;
      int n2 = tile2/196, rem2 = tile2%196, br2 = rem2/14, bc2 = rem2%14;
      int y0 = br2*16 - 1, x0 = bc2*16 - 1;
      const __half* hn = h1t + (size_t)n2*HWP*16;
      #pragma unroll
      for (int it = 0; it < 3; ++it) {
        int w = min(tid + it*256, 647);
        int p = w >> 1, hh = w & 1;
        int gy = min(max(y0 + p/18, 0), HH-1);
        int gx = min(max(x0 + p%18, 0), HWD-1);
        st[it] = ntld_u4(hn + ((size_t)(gy*HWD + gx))*16 + hh*8);
      }
      #pragma unroll
      for (int ty = 0; ty < 4; ++ty)
        sv[ty] = __builtin_nontemporal_load(
            sel + (size_t)n2*HWP + (br2*16 + wid*4 + ty)*HWD + bc2*16 + r);
    }
    __syncthreads();                                 // bar_A: buf[cur] ready; pl free
    // ---- MFMA phase (reads ts[cur]) ----
    f32x4 acc[4] = {{0,0,0,0},{0,0,0,0},{0,0,0,0},{0,0,0,0}};
    #pragma unroll
    for (int p = 0; p < 5; ++p) {
      int ta = 2*p, tb = (2*p+1 > 8) ? 8 : 2*p+1;
      int dyL = tapPar ? tb/3 : ta/3;
      int dxL = tapPar ? tb%3 : ta%3;
      int shL = 3*(tapPar ? 2*p+1 : 2*p);
      uint4 a[4];
      #pragma unroll
      for (int ty = 0; ty < 4; ++ty) {
        int ly = wid*4 + ty;
        a[ty] = *(const uint4*)(&ts[cur][0] + ((ly + dyL)*18 + (r + dxL))*24 + c0);
      }
      #pragma unroll
      for (int j = 0; j < 3; ++j) {
        uint4 bf = wlds[(p*3 + j)*64 + lane];
        #pragma unroll
        for (int ty = 0; ty < 4; ++ty) {
          uint32_t msk = 0u - ((svc[ty] >> (shL + j)) & 1u);
          uint4 am = { a[ty].x & msk, a[ty].y & msk, a[ty].z & msk, a[ty].w & msk };
          acc[ty] = mfma16(am, bf, acc[ty]);
        }
      }
    }
    // ---- relu + 2x2 maxpool -> pl ----
    #pragma unroll
    for (int yp = 0; yp < 2; ++yp) {
      f32x4 v0 = acc[yp*2], v1 = acc[yp*2+1];
      float m00 = fmaxf(fmaxf(v0[0]+bo, 0.f), fmaxf(v0[1]+bo, 0.f));
      float m01 = fmaxf(fmaxf(v0[2]+bo, 0.f), fmaxf(v0[3]+bo, 0.f));
      float m10 = fmaxf(fmaxf(v1[0]+bo, 0.f), fmaxf(v1[1]+bo, 0.f));
      float m11 = fmaxf(fmaxf(v1[2]+bo, 0.f), fmaxf(v1[3]+bo, 0.f));
      int prow = wid*2 + yp;
      int pc0 = (lane >> 4)*2;
      pl[(prow*8 + pc0)*17 + r]     = fmaxf(m00, m10);
      pl[(prow*8 + pc0 + 1)*17 + r] = fmaxf(m01, m11);
    }
    __syncthreads();                                 // bar_B: pl ready
    for (int t = tid; t < 1024; t += 256) {          // repack channel-first f16
      int oo = t >> 6; int pix = t & 63;
      int pr = pix >> 3, pc = pix & 7;
      pooled[(size_t)(n*16 + oo)*PHW + (br*8 + pr)*PW + bc*8 + pc] =
          __float2half(pl[pix*17 + oo]);
    }
    // next pl writes occur after next iter's bar_A -> ordered vs these reads
  }
}

// ---------------- FC1 via MFMA: 2 otiles (32 outputs) per block ----------------
// XCD swizzle: same-kseg grp-quads land on one XCD so the A slice is fetched
// once per XCD L2 (A HBM traffic 25.7 -> ~6.4 MB). W loads non-temporal.
__global__ __launch_bounds__(256) void fc1_kernel(
    const __half* __restrict__ hin, const float* __restrict__ wgt,
    float* __restrict__ partial) {
  __shared__ __align__(16) uint4 alds[2][256];     //  8 KB
  __shared__ __align__(16) uint4 wlds[2][2][256];  // 16 KB [buf][g][slot]
  __shared__ __align__(16) f32x4 cacc[2][256];     //  8 KB
  int tid = threadIdx.x;
  int b = blockIdx.x;
  int snum = (b & 7)*98 + (b >> 3);   // bijective: 784 = 8 * 98
  int kseg = snum >> 2;
  int grp  = snum & 3;
  int obase = grp * 32;
  int lane = tid & 63, wid = tid >> 6;
  int q8 = tid & 15, row = tid >> 4;              // 16 rows x 16 k-octs
  int sslot = (q8>>2)*64 + (row | ((q8&3) << 4));
  const __half* hp0 = hin + (size_t)row*FCK + kseg*1024 + q8*8;
  const float* wq0  = wgt + (size_t)(obase + row)*FCK + kseg*1024 + q8*8;
  const float* wq1  = wgt + (size_t)(obase + 16 + row)*FCK + kseg*1024 + q8*8;
  uint4 hv; float4 w0a, w0b, w1a, w1b;
  hv  = *(const uint4*)hp0;
  w0a = ntld_f4(wq0); w0b = ntld_f4(wq0 + 4);
  w1a = ntld_f4(wq1); w1b = ntld_f4(wq1 + 4);
  f32x4 acc0 = {0,0,0,0}, acc1 = {0,0,0,0};
  for (int ch = 0; ch < 8; ++ch) {
    int buf = ch & 1;
    alds[buf][sslot] = hv;
    wlds[buf][0][sslot] = (uint4){ pkh2(w0a.x,w0a.y), pkh2(w0a.z,w0a.w),
                                   pkh2(w0b.x,w0b.y), pkh2(w0b.z,w0b.w) };
    wlds[buf][1][sslot] = (uint4){ pkh2(w1a.x,w1a.y), pkh2(w1a.z,w1a.w),
                                   pkh2(w1b.x,w1b.y), pkh2(w1b.z,w1b.w) };
    if (ch < 7) {                                  // next chunk's loads pre-barrier
      hv  = *(const uint4*)(hp0 + (ch+1)*128);
      w0a = ntld_f4(wq0 + (ch+1)*128); w0b = ntld_f4(wq0 + (ch+1)*128 + 4);
      w1a = ntld_f4(wq1 + (ch+1)*128); w1b = ntld_f4(wq1 + (ch+1)*128 + 4);
    }
    __syncthreads();
    uint4 av = alds[buf][wid*64 + lane];
    acc0 = mfma16(av, wlds[buf][0][wid*64 + lane], acc0);
    acc1 = mfma16(av, wlds[buf][1][wid*64 + lane], acc1);
  }
  cacc[0][wid*64 + lane] = acc0;
  cacc[1][wid*64 + lane] = acc1;
  __syncthreads();
  {
    int l = tid & 63, e = tid >> 6;
    int nn = (l >> 4)*4 + e;
    int oo = l & 15;
    #pragma unroll
    for (int g = 0; g < 2; ++g) {
      float s = cacc[g][l][e] + cacc[g][64 + l][e] + cacc[g][128 + l][e] + cacc[g][192 + l][e];
      partial[((size_t)kseg*16 + nn)*128 + obase + g*16 + oo] = s;
    }
  }
}

// ---------------- FC2 (+fused fc1-reduce) + log_softmax, parallelized ----------------
__global__ __launch_bounds__(256) void fc2_kernel(
    const float* __restrict__ partial, const float* __restrict__ fc1b,
    const float* __restrict__ w, const float* __restrict__ b,
    float* __restrict__ out) {
  __shared__ float psum[256];
  __shared__ float row[128];
  __shared__ float v[10];
  __shared__ float lse;
  int n = blockIdx.x, t = threadIdx.x;
  // phase 1: kseg reduce, 2 threads per output (98 ksegs each)
  {
    int o = t & 127, half = t >> 7;
    const float* pp = partial + ((size_t)(half*98)*16 + n)*128 + o;
    float s = 0.f;
    for (int k = 0; k < 98; ++k)
      s += __builtin_nontemporal_load(pp + (size_t)k*2048);
    psum[t] = s;
  }
  __syncthreads();
  if (t < 128) row[t] = fc1b[t] + psum[t] + psum[t + 128];
  __syncthreads();
  // phase 2: 10 dot-products, one per wave-slot, wave-shuffle reduce
  {
    int wv = t >> 6, lane = t & 63;
    for (int d = wv; d < 10; d += 4) {
      float acc = w[d*128 + lane]*row[lane] + w[d*128 + 64 + lane]*row[64 + lane];
      acc += __shfl_xor(acc, 1);  acc += __shfl_xor(acc, 2);
      acc += __shfl_xor(acc, 4);  acc += __shfl_xor(acc, 8);
      acc += __shfl_xor(acc, 16); acc += __shfl_xor(acc, 32);
      if (lane == 0) v[d] = acc + b[d];
    }
  }
  __syncthreads();
  if (t == 0) {
    float m = v[0];
    for (int i = 1; i < 10; ++i) m = fmaxf(m, v[i]);
    float se = 0.f;
    for (int i = 0; i < 10; ++i) se += expf(v[i] - m);
    lse = m + logf(se);
  }
  __syncthreads();
  if (t < 10) out[n*10 + t] = v[t] - lse;
}

extern "C" void kernel_launch(void* const* d_in, const int* in_sizes, int n_in,
                              void* d_out, int out_size, void* d_ws, size_t ws_size,
                              hipStream_t stream) {
  const float* x     = (const float*)d_in[0];
  const float* depth = (const float*)d_in[1];
  const float* fx    = (const float*)d_in[2];
  const float* c1w0  = (const float*)d_in[3];
  const float* c1w1  = (const float*)d_in[4];
  const float* c1w2  = (const float*)d_in[5];
  const float* c1b   = (const float*)d_in[6];
  const float* c2w0  = (const float*)d_in[7];
  const float* c2w1  = (const float*)d_in[8];
  const float* c2w2  = (const float*)d_in[9];
  const float* c2b   = (const float*)d_in[10];
  const float* fc1w  = (const float*)d_in[11];
  const float* fc1b  = (const float*)d_in[12];
  const float* fc2w  = (const float*)d_in[13];
  const float* fc2b  = (const float*)d_in[14];
  float* out = (float*)d_out;

  char* ws = (char*)d_ws;
  uint32_t* sel  = (uint32_t*)ws;                      // 3,211,264 B
  __half* h1t    = (__half*)(ws + 3211264);            // 25,690,112 B
  __half* pooled = (__half*)(ws + 28901376);           //  6,422,528 B
  float* partial = (float*)(ws + 35323904);            //  1,605,632 B

  conv1_kernel<<<784, 256, 0, stream>>>(x, depth, fx, c1w0, c1w1, c1w2, c1b, sel, h1t);
  conv2_kernel<<<784, 256, 0, stream>>>(h1t, sel, c2w0, c2w1, c2w2, c2b, pooled);
  fc1_kernel<<<784, 256, 0, stream>>>(pooled, fc1w, partial);
  fc2_kernel<<<16, 256, 0, stream>>>(partial, fc1b, fc2w, fc2b, out);
}

// Round 10
// 112.901 us; speedup vs baseline: 1.0030x; 1.0030x over previous
//
#include <hip/hip_runtime.h>
#include <hip/hip_fp16.h>
#include <stdint.h>

#define HH 224
#define HWD 224
#define HWP (HH*HWD)      // 50176
#define PH 112
#define PW 112
#define PHW (PH*PW)       // 12544
#define FCK 200704
#define KSEG 196

typedef _Float16 f16x8 __attribute__((ext_vector_type(8)));
typedef float f32x4 __attribute__((ext_vector_type(4)));
typedef float f32x4v __attribute__((ext_vector_type(4)));

static __device__ __forceinline__ uint32_t pkh2(float a, float b) {
  __half2 h = __floats2half2_rn(a, b);
  return __builtin_bit_cast(uint32_t, h);
}
static __device__ __forceinline__ f32x4 mfma16(uint4 a, uint4 b, f32x4 c) {
  return __builtin_amdgcn_mfma_f32_16x16x32_f16(
      __builtin_bit_cast(f16x8, a), __builtin_bit_cast(f16x8, b), c, 0, 0, 0);
}
static __device__ __forceinline__ float4 ntld_f4(const void* p) {
  f32x4v v = __builtin_nontemporal_load((const f32x4v*)p);
  return make_float4(v.x, v.y, v.z, v.w);
}

// ======== MFMA conv template (validated R4-R8) ========
// A (M=16 px along x, K=32 = 2 taps x 16 c): lane l -> px r=l&15, tap parity l>>5,
//   c = ((l>>4)&1)*8 + e.  B: lane l -> o=l&15, same K map.  C/D: o=l&15, px=(l>>4)*4+reg.
// Mask m_j[px,tap] uniform over lane's 8 A elems -> AND-mask on A fragment.
// R10: convs are EXACTLY R8 (single ts buffer, 3 barriers/tile, (256,4), plain
// loads) -- R9's nt/dbuf conv bundle regressed +8.5us and is reverted.
// Kept from R9: fc1 XCD swizzle + nt on the 103MB W stream; parallel fc2.

// ---------------- conv1 (+fused sel): 3->16 via MFMA ----------------
__global__ __launch_bounds__(256, 4) void conv1_kernel(
    const float* __restrict__ x, const float* __restrict__ depth,
    const float* __restrict__ fxp,
    const float* __restrict__ w0, const float* __restrict__ w1,
    const float* __restrict__ w2, const float* __restrict__ bias,
    uint32_t* __restrict__ sel, __half* __restrict__ h1t) {
  __shared__ __align__(16) __half ts[324*24];     // 15552 B  [py][px][c pad 24]
  __shared__ __align__(16) uint4 wlds[15*64];     // 15360 B  B-frags
  __shared__ float dt[324];                       //  1296 B  depth tile (0-filled OOB)
  __shared__ uint32_t sbits[256];                 //  1024 B  sel bits of 16x16 tile
  __shared__ __align__(16) __half hbuf[1024];     //  2048 B  epilogue bounce
  int tid = threadIdx.x;
  int lane = tid & 63, wid = tid >> 6;
  int r = lane & 15;
  int tapPar = lane >> 5;
  int c0 = ((lane >> 4) & 1) * 8;
  float bo = bias[r];
  float fx = fxp[0];

  // ---- stage B-frags once into LDS (branchless clamped loads) ----
  #pragma unroll
  for (int it = 0; it < 4; ++it) {
    int t = tid + it*256;
    int tc = min(t, 959);
    int ln = tc & 63; int pj = tc >> 6;
    int p = pj / 3, j = pj % 3;
    int o = ln & 15; int tap = p*2 + (ln >> 5);
    int cbase = ((ln >> 4) & 1) * 8;
    const float* wj = (j == 0) ? w0 : (j == 1) ? w1 : w2;
    float f[8];
    #pragma unroll
    for (int e = 0; e < 8; ++e) {
      int c = cbase + e;
      float v = wj[o*27 + min(c,2)*9 + min(tap,8)];
      f[e] = (tap <= 8 && c < 3) ? v : 0.f;
    }
    if (t < 960) {
      uint4 wv = { pkh2(f[0],f[1]), pkh2(f[2],f[3]), pkh2(f[4],f[5]), pkh2(f[6],f[7]) };
      wlds[pj*64 + ln] = wv;
    }
  }

  // ---- prefetch tile 0 (x + depth) ----
  int tbase = blockIdx.x * 4;
  float pf[2][3]; float pd[2];
  {
    int tile = tbase;
    int n = tile/196, rem = tile%196, br = rem/14, bc = rem%14;
    int y0 = br*16 - 1, x0 = bc*16 - 1;
    const float* xn = x + (size_t)n*3*HWP;
    const float* dn = depth + (size_t)n*HWP;
    #pragma unroll
    for (int it = 0; it < 2; ++it) {
      int p = min(tid + it*256, 323);
      int yy = y0 + p/18, xx = x0 + p%18;
      int gy = min(max(yy,0),HH-1), gx = min(max(xx,0),HWD-1);
      size_t off = (size_t)gy*HWD + gx;
      pf[it][0] = xn[off]; pf[it][1] = xn[HWP+off]; pf[it][2] = xn[2*HWP+off];
      float dv = dn[off];
      pd[it] = (yy>=0 && yy<HH && xx>=0 && xx<HWD) ? dv : 0.f;  // true 0-pad
    }
  }

  for (int ti = 0; ti < 4; ++ti) {
    int tile = tbase + ti;
    int n = tile/196, rem = tile%196, br = rem/14, bc = rem%14;
    // ---- ds_write current tile (x f16-padded + depth f32) ----
    #pragma unroll
    for (int it = 0; it < 2; ++it) {
      int p = tid + it*256;
      if (p < 324) {
        uint4 v0 = { pkh2(pf[it][0], pf[it][1]), pkh2(pf[it][2], 0.f), 0u, 0u };
        uint4 z  = { 0u, 0u, 0u, 0u };
        *(uint4*)(ts + p*24)      = v0;
        *(uint4*)(ts + p*24 + 8)  = z;
        *(uint4*)(ts + p*24 + 16) = z;
        dt[p] = pd[it];
      }
    }
    // ---- issue next tile's global loads ----
    if (ti < 3) {
      int tile2 = tile + 1;
      int n2 = tile2/196, rem2 = tile2%196, br2 = rem2/14, bc2 = rem2%14;
      int y0 = br2*16 - 1, x0 = bc2*16 - 1;
      const float* xn = x + (size_t)n2*3*HWP;
      const float* dn = depth + (size_t)n2*HWP;
      #pragma unroll
      for (int it = 0; it < 2; ++it) {
        int p = min(tid + it*256, 323);
        int yy = y0 + p/18, xx = x0 + p%18;
        int gy = min(max(yy,0),HH-1), gx = min(max(xx,0),HWD-1);
        size_t off = (size_t)gy*HWD + gx;
        pf[it][0] = xn[off]; pf[it][1] = xn[HWP+off]; pf[it][2] = xn[2*HWP+off];
        float dv = dn[off];
        pd[it] = (yy>=0 && yy<HH && xx>=0 && xx<HWD) ? dv : 0.f;
      }
    }
    __syncthreads();
    // ---- sel bits for this 16x16 tile (math == validated sel_kernel) ----
    {
      int py = tid >> 4, px = tid & 15;
      float c = dt[(py+1)*18 + (px+1)];
      float gr = c / fx;
      float hf = gr * 0.5f;
      uint32_t bits = 0;
      #pragma unroll
      for (int i = 0; i < 3; ++i)
        #pragma unroll
        for (int j = 0; j < 3; ++j) {
          float d = dt[(py+i)*18 + (px+j)];
          int k = i*3 + j;
          uint32_t bb = 0;
          if (fabsf(d - (c + gr)) <= hf) bb |= 1u;
          if (fabsf(d - c) < hf)         bb |= 2u;
          if (fabsf(d - (c - gr)) <= hf) bb |= 4u;
          bits |= bb << (3*k);
        }
      sbits[tid] = bits;
      sel[(size_t)n*HWP + (br*16 + py)*HWD + bc*16 + px] = bits;  // for conv2
    }
    __syncthreads();
    uint32_t svc[4];
    #pragma unroll
    for (int ty = 0; ty < 4; ++ty) svc[ty] = sbits[(wid*4 + ty)*16 + r];
    // ---- MFMA phase ----
    f32x4 acc[4] = {{0,0,0,0},{0,0,0,0},{0,0,0,0},{0,0,0,0}};
    #pragma unroll
    for (int p = 0; p < 5; ++p) {
      int ta = 2*p, tb = (2*p+1 > 8) ? 8 : 2*p+1;   // tap9 dups tap8 (B=0 kills it)
      int dyL = tapPar ? tb/3 : ta/3;
      int dxL = tapPar ? tb%3 : ta%3;
      int shL = 3*(tapPar ? 2*p+1 : 2*p);
      uint4 a[4];
      #pragma unroll
      for (int ty = 0; ty < 4; ++ty) {
        int ly = wid*4 + ty;
        a[ty] = *(const uint4*)(ts + ((ly + dyL)*18 + (r + dxL))*24 + c0);
      }
      #pragma unroll
      for (int j = 0; j < 3; ++j) {
        uint4 bf = wlds[(p*3 + j)*64 + lane];
        #pragma unroll
        for (int ty = 0; ty < 4; ++ty) {
          uint32_t msk = 0u - ((svc[ty] >> (shL + j)) & 1u);
          uint4 am = { a[ty].x & msk, a[ty].y & msk, a[ty].z & msk, a[ty].w & msk };
          acc[ty] = mfma16(am, bf, acc[ty]);
        }
      }
    }
    // ---- epilogue: relu + channel-last f16 store via hbuf bounce ----
    #pragma unroll
    for (int ty = 0; ty < 4; ++ty) {
      int gy = br*16 + wid*4 + ty;
      #pragma unroll
      for (int e = 0; e < 4; ++e) {
        float v = fmaxf(acc[ty][e] + bo, 0.f);
        hbuf[wid*256 + ((lane>>4)*4 + e)*16 + r] = __float2half(v);
      }
      uint2 hw = *(uint2*)&hbuf[wid*256 + lane*4];
      *(uint2*)(h1t + ((size_t)(n*HWP + gy*HWD) + bc*16)*16 + lane*4) = hw;
    }
    __syncthreads();   // ts/dt/sbits/hbuf reads done before next tile's writes
  }
}

// ---------------- conv2: 16->16 via MFMA + ReLU + 2x2 maxpool -> pooled f16 CF ----------------
__global__ __launch_bounds__(256, 4) void conv2_kernel(
    const __half* __restrict__ h1t, const uint32_t* __restrict__ sel,
    const float* __restrict__ w0, const float* __restrict__ w1,
    const float* __restrict__ w2, const float* __restrict__ bias,
    __half* __restrict__ pooled) {
  __shared__ __align__(16) __half ts[324*24];     // 15552 B
  __shared__ __align__(16) uint4 wlds[15*64];     // 15360 B
  __shared__ float pl[64*17];                     //  4352 B
  int tid = threadIdx.x;
  int lane = tid & 63, wid = tid >> 6;
  int r = lane & 15;
  int tapPar = lane >> 5;
  int c0 = ((lane >> 4) & 1) * 8;
  float bo = bias[r];

  // ---- stage B-frags once into LDS ----
  #pragma unroll
  for (int it = 0; it < 4; ++it) {
    int t = tid + it*256;
    int tc = min(t, 959);
    int ln = tc & 63; int pj = tc >> 6;
    int p = pj / 3, j = pj % 3;
    int o = ln & 15; int tap = p*2 + (ln >> 5);
    int cbase = ((ln >> 4) & 1) * 8;
    const float* wj = (j == 0) ? w0 : (j == 1) ? w1 : w2;
    const float* wp = wj + o*144 + cbase*9 + tap;   // [o][c][k]; tap=9 stays in-bounds
    float f[8];
    #pragma unroll
    for (int e = 0; e < 8; ++e) {
      float v = wp[e*9];
      f[e] = (tap <= 8) ? v : 0.f;
    }
    if (t < 960) {
      uint4 wv = { pkh2(f[0],f[1]), pkh2(f[2],f[3]), pkh2(f[4],f[5]), pkh2(f[6],f[7]) };
      wlds[pj*64 + ln] = wv;
    }
  }

  // ---- prefetch tile 0 ----
  int tbase = blockIdx.x * 4;
  uint4 st[3]; uint32_t sv[4];
  {
    int tile = tbase;
    int n = tile/196, rem = tile%196, br = rem/14, bc = rem%14;
    int y0 = br*16 - 1, x0 = bc*16 - 1;
    const __half* hn = h1t + (size_t)n*HWP*16;
    #pragma unroll
    for (int it = 0; it < 3; ++it) {
      int w = min(tid + it*256, 647);
      int p = w >> 1, hh = w & 1;
      int gy = min(max(y0 + p/18, 0), HH-1);
      int gx = min(max(x0 + p%18, 0), HWD-1);
      st[it] = *(const uint4*)(hn + ((size_t)(gy*HWD + gx))*16 + hh*8);
    }
    #pragma unroll
    for (int ty = 0; ty < 4; ++ty)
      sv[ty] = sel[(size_t)n*HWP + (br*16 + wid*4 + ty)*HWD + bc*16 + r];
  }

  for (int ti = 0; ti < 4; ++ti) {
    int tile = tbase + ti;
    int n = tile/196, rem = tile%196, br = rem/14, bc = rem%14;
    // ---- ds_write current tile ----
    #pragma unroll
    for (int it = 0; it < 3; ++it) {
      int w = tid + it*256;
      if (w < 648) {
        int p = w >> 1, hh = w & 1;
        *(uint4*)(ts + p*24 + hh*8) = st[it];
      }
    }
    uint32_t svc[4];
    #pragma unroll
    for (int ty = 0; ty < 4; ++ty) svc[ty] = sv[ty];
    // ---- issue next tile's loads ----
    if (ti < 3) {
      int tile2 = tile + 1;
      int n2 = tile2/196, rem2 = tile2%196, br2 = rem2/14, bc2 = rem2%14;
      int y0 = br2*16 - 1, x0 = bc2*16 - 1;
      const __half* hn = h1t + (size_t)n2*HWP*16;
      #pragma unroll
      for (int it = 0; it < 3; ++it) {
        int w = min(tid + it*256, 647);
        int p = w >> 1, hh = w & 1;
        int gy = min(max(y0 + p/18, 0), HH-1);
        int gx = min(max(x0 + p%18, 0), HWD-1);
        st[it] = *(const uint4*)(hn + ((size_t)(gy*HWD + gx))*16 + hh*8);
      }
      #pragma unroll
      for (int ty = 0; ty < 4; ++ty)
        sv[ty] = sel[(size_t)n2*HWP + (br2*16 + wid*4 + ty)*HWD + bc2*16 + r];
    }
    __syncthreads();
    // ---- MFMA phase ----
    f32x4 acc[4] = {{0,0,0,0},{0,0,0,0},{0,0,0,0},{0,0,0,0}};
    #pragma unroll
    for (int p = 0; p < 5; ++p) {
      int ta = 2*p, tb = (2*p+1 > 8) ? 8 : 2*p+1;
      int dyL = tapPar ? tb/3 : ta/3;
      int dxL = tapPar ? tb%3 : ta%3;
      int shL = 3*(tapPar ? 2*p+1 : 2*p);
      uint4 a[4];
      #pragma unroll
      for (int ty = 0; ty < 4; ++ty) {
        int ly = wid*4 + ty;
        a[ty] = *(const uint4*)(ts + ((ly + dyL)*18 + (r + dxL))*24 + c0);
      }
      #pragma unroll
      for (int j = 0; j < 3; ++j) {
        uint4 bf = wlds[(p*3 + j)*64 + lane];
        #pragma unroll
        for (int ty = 0; ty < 4; ++ty) {
          uint32_t msk = 0u - ((svc[ty] >> (shL + j)) & 1u);
          uint4 am = { a[ty].x & msk, a[ty].y & msk, a[ty].z & msk, a[ty].w & msk };
          acc[ty] = mfma16(am, bf, acc[ty]);
        }
      }
    }
    // ---- relu + 2x2 maxpool -> pl ----
    #pragma unroll
    for (int yp = 0; yp < 2; ++yp) {
      f32x4 v0 = acc[yp*2], v1 = acc[yp*2+1];
      float m00 = fmaxf(fmaxf(v0[0]+bo, 0.f), fmaxf(v0[1]+bo, 0.f));
      float m01 = fmaxf(fmaxf(v0[2]+bo, 0.f), fmaxf(v0[3]+bo, 0.f));
      float m10 = fmaxf(fmaxf(v1[0]+bo, 0.f), fmaxf(v1[1]+bo, 0.f));
      float m11 = fmaxf(fmaxf(v1[2]+bo, 0.f), fmaxf(v1[3]+bo, 0.f));
      int prow = wid*2 + yp;
      int pc0 = (lane >> 4)*2;
      pl[(prow*8 + pc0)*17 + r]     = fmaxf(m00, m10);
      pl[(prow*8 + pc0 + 1)*17 + r] = fmaxf(m01, m11);
    }
    __syncthreads();   // pl ready; also all ts reads done
    for (int t = tid; t < 1024; t += 256) {       // repack channel-first f16
      int oo = t >> 6; int pix = t & 63;
      int pr = pix >> 3, pc = pix & 7;
      pooled[(size_t)(n*16 + oo)*PHW + (br*8 + pr)*PW + bc*8 + pc] =
          __float2half(pl[pix*17 + oo]);
    }
    __syncthreads();   // pl reads done before next tile's writes
  }
}

// ---------------- FC1 via MFMA: 2 otiles (32 outputs) per block ----------------
// XCD swizzle: same-kseg grp-quads land on one XCD -> A slice fetched once per
// XCD L2. W stream (103MB, read-once) non-temporal so it doesn't evict A/partial.
__global__ __launch_bounds__(256) void fc1_kernel(
    const __half* __restrict__ hin, const float* __restrict__ wgt,
    float* __restrict__ partial) {
  __shared__ __align__(16) uint4 alds[2][256];     //  8 KB
  __shared__ __align__(16) uint4 wlds[2][2][256];  // 16 KB [buf][g][slot]
  __shared__ __align__(16) f32x4 cacc[2][256];     //  8 KB
  int tid = threadIdx.x;
  int b = blockIdx.x;
  int snum = (b & 7)*98 + (b >> 3);   // bijective: 784 = 8 * 98
  int kseg = snum >> 2;
  int grp  = snum & 3;
  int obase = grp * 32;
  int lane = tid & 63, wid = tid >> 6;
  int q8 = tid & 15, row = tid >> 4;              // 16 rows x 16 k-octs
  int sslot = (q8>>2)*64 + (row | ((q8&3) << 4));
  const __half* hp0 = hin + (size_t)row*FCK + kseg*1024 + q8*8;
  const float* wq0  = wgt + (size_t)(obase + row)*FCK + kseg*1024 + q8*8;
  const float* wq1  = wgt + (size_t)(obase + 16 + row)*FCK + kseg*1024 + q8*8;
  uint4 hv; float4 w0a, w0b, w1a, w1b;
  hv  = *(const uint4*)hp0;
  w0a = ntld_f4(wq0); w0b = ntld_f4(wq0 + 4);
  w1a = ntld_f4(wq1); w1b = ntld_f4(wq1 + 4);
  f32x4 acc0 = {0,0,0,0}, acc1 = {0,0,0,0};
  for (int ch = 0; ch < 8; ++ch) {
    int buf = ch & 1;
    alds[buf][sslot] = hv;
    wlds[buf][0][sslot] = (uint4){ pkh2(w0a.x,w0a.y), pkh2(w0a.z,w0a.w),
                                   pkh2(w0b.x,w0b.y), pkh2(w0b.z,w0b.w) };
    wlds[buf][1][sslot] = (uint4){ pkh2(w1a.x,w1a.y), pkh2(w1a.z,w1a.w),
                                   pkh2(w1b.x,w1b.y), pkh2(w1b.z,w1b.w) };
    if (ch < 7) {                                  // next chunk's loads pre-barrier
      hv  = *(const uint4*)(hp0 + (ch+1)*128);
      w0a = ntld_f4(wq0 + (ch+1)*128); w0b = ntld_f4(wq0 + (ch+1)*128 + 4);
      w1a = ntld_f4(wq1 + (ch+1)*128); w1b = ntld_f4(wq1 + (ch+1)*128 + 4);
    }
    __syncthreads();
    uint4 av = alds[buf][wid*64 + lane];
    acc0 = mfma16(av, wlds[buf][0][wid*64 + lane], acc0);
    acc1 = mfma16(av, wlds[buf][1][wid*64 + lane], acc1);
  }
  cacc[0][wid*64 + lane] = acc0;
  cacc[1][wid*64 + lane] = acc1;
  __syncthreads();
  {
    int l = tid & 63, e = tid >> 6;
    int nn = (l >> 4)*4 + e;
    int oo = l & 15;
    #pragma unroll
    for (int g = 0; g < 2; ++g) {
      float s = cacc[g][l][e] + cacc[g][64 + l][e] + cacc[g][128 + l][e] + cacc[g][192 + l][e];
      partial[((size_t)kseg*16 + nn)*128 + obase + g*16 + oo] = s;
    }
  }
}

// ---------------- FC2 (+fused fc1-reduce) + log_softmax, parallelized ----------------
__global__ __launch_bounds__(256) void fc2_kernel(
    const float* __restrict__ partial, const float* __restrict__ fc1b,
    const float* __restrict__ w, const float* __restrict__ b,
    float* __restrict__ out) {
  __shared__ float psum[256];
  __shared__ float row[128];
  __shared__ float v[10];
  __shared__ float lse;
  int n = blockIdx.x, t = threadIdx.x;
  // phase 1: kseg reduce, 2 threads per output (98 ksegs each)
  {
    int o = t & 127, half = t >> 7;
    const float* pp = partial + ((size_t)(half*98)*16 + n)*128 + o;
    float s = 0.f;
    for (int k = 0; k < 98; ++k) s += pp[(size_t)k*2048];
    psum[t] = s;
  }
  __syncthreads();
  if (t < 128) row[t] = fc1b[t] + psum[t] + psum[t + 128];
  __syncthreads();
  // phase 2: 10 dot-products, one per wave-slot, wave-shuffle reduce
  {
    int wv = t >> 6, lane = t & 63;
    for (int d = wv; d < 10; d += 4) {
      float acc = w[d*128 + lane]*row[lane] + w[d*128 + 64 + lane]*row[64 + lane];
      acc += __shfl_xor(acc, 1);  acc += __shfl_xor(acc, 2);
      acc += __shfl_xor(acc, 4);  acc += __shfl_xor(acc, 8);
      acc += __shfl_xor(acc, 16); acc += __shfl_xor(acc, 32);
      if (lane == 0) v[d] = acc + b[d];
    }
  }
  __syncthreads();
  if (t == 0) {
    float m = v[0];
    for (int i = 1; i < 10; ++i) m = fmaxf(m, v[i]);
    float se = 0.f;
    for (int i = 0; i < 10; ++i) se += expf(v[i] - m);
    lse = m + logf(se);
  }
  __syncthreads();
  if (t < 10) out[n*10 + t] = v[t] - lse;
}

extern "C" void kernel_launch(void* const* d_in, const int* in_sizes, int n_in,
                              void* d_out, int out_size, void* d_ws, size_t ws_size,
                              hipStream_t stream) {
  const float* x     = (const float*)d_in[0];
  const float* depth = (const float*)d_in[1];
  const float* fx    = (const float*)d_in[2];
  const float* c1w0  = (const float*)d_in[3];
  const float* c1w1  = (const float*)d_in[4];
  const float* c1w2  = (const float*)d_in[5];
  const float* c1b   = (const float*)d_in[6];
  const float* c2w0  = (const float*)d_in[7];
  const float* c2w1  = (const float*)d_in[8];
  const float* c2w2  = (const float*)d_in[9];
  const float* c2b   = (const float*)d_in[10];
  const float* fc1w  = (const float*)d_in[11];
  const float* fc1b  = (const float*)d_in[12];
  const float* fc2w  = (const float*)d_in[13];
  const float* fc2b  = (const float*)d_in[14];
  float* out = (float*)d_out;

  char* ws = (char*)d_ws;
  uint32_t* sel  = (uint32_t*)ws;                      // 3,211,264 B
  __half* h1t    = (__half*)(ws + 3211264);            // 25,690,112 B
  __half* pooled = (__half*)(ws + 28901376);           //  6,422,528 B
  float* partial = (float*)(ws + 35323904);            //  1,605,632 B

  conv1_kernel<<<784, 256, 0, stream>>>(x, depth, fx, c1w0, c1w1, c1w2, c1b, sel, h1t);
  conv2_kernel<<<784, 256, 0, stream>>>(h1t, sel, c2w0, c2w1, c2w2, c2b, pooled);
  fc1_kernel<<<784, 256, 0, stream>>>(pooled, fc1w, partial);
  fc2_kernel<<<16, 256, 0, stream>>>(partial, fc1b, fc2w, fc2b, out);
}

// Round 11
// 99.916 us; speedup vs baseline: 1.1333x; 1.1300x over previous
//
#include <hip/hip_runtime.h>
#include <hip/hip_fp16.h>
#include <stdint.h>

#define HH 224
#define HWD 224
#define HWP (HH*HWD)      // 50176
#define PH 112
#define PW 112
#define PHW (PH*PW)       // 12544
#define FCK 200704
#define KSEG 196

typedef _Float16 f16x8 __attribute__((ext_vector_type(8)));
typedef float f32x4 __attribute__((ext_vector_type(4)));

static __device__ __forceinline__ uint32_t pkh2(float a, float b) {
  __half2 h = __floats2half2_rn(a, b);
  return __builtin_bit_cast(uint32_t, h);
}
static __device__ __forceinline__ f32x4 mfma16(uint4 a, uint4 b, f32x4 c) {
  return __builtin_amdgcn_mfma_f32_16x16x32_f16(
      __builtin_bit_cast(f16x8, a), __builtin_bit_cast(f16x8, b), c, 0, 0, 0);
}

// ======== MFMA conv template (validated R4-R8) ========
// A (M=16 px along x, K=32 = 2 taps x 16 c): lane l -> px r=l&15, tap parity l>>5,
//   c = ((l>>4)&1)*8 + e.  B: lane l -> o=l&15, same K map.  C/D: o=l&15, px=(l>>4)*4+reg.
// Mask m_j[px,tap] uniform over lane's 8 A elems -> AND-mask on A fragment.
// R11: single-variable bisect step -- fc1 W loads back to PLAIN (R10's nt
// forfeited L3 residency across graph replays: ~143MB working set < 256MB L3,
// so the 103MB W stream was L3-served until nt marked it evict-first).
// Convs = exact R8. fc1 XCD swizzle + parallel fc2 kept.

// ---------------- conv1 (+fused sel): 3->16 via MFMA ----------------
__global__ __launch_bounds__(256, 4) void conv1_kernel(
    const float* __restrict__ x, const float* __restrict__ depth,
    const float* __restrict__ fxp,
    const float* __restrict__ w0, const float* __restrict__ w1,
    const float* __restrict__ w2, const float* __restrict__ bias,
    uint32_t* __restrict__ sel, __half* __restrict__ h1t) {
  __shared__ __align__(16) __half ts[324*24];     // 15552 B  [py][px][c pad 24]
  __shared__ __align__(16) uint4 wlds[15*64];     // 15360 B  B-frags
  __shared__ float dt[324];                       //  1296 B  depth tile (0-filled OOB)
  __shared__ uint32_t sbits[256];                 //  1024 B  sel bits of 16x16 tile
  __shared__ __align__(16) __half hbuf[1024];     //  2048 B  epilogue bounce
  int tid = threadIdx.x;
  int lane = tid & 63, wid = tid >> 6;
  int r = lane & 15;
  int tapPar = lane >> 5;
  int c0 = ((lane >> 4) & 1) * 8;
  float bo = bias[r];
  float fx = fxp[0];

  // ---- stage B-frags once into LDS (branchless clamped loads) ----
  #pragma unroll
  for (int it = 0; it < 4; ++it) {
    int t = tid + it*256;
    int tc = min(t, 959);
    int ln = tc & 63; int pj = tc >> 6;
    int p = pj / 3, j = pj % 3;
    int o = ln & 15; int tap = p*2 + (ln >> 5);
    int cbase = ((ln >> 4) & 1) * 8;
    const float* wj = (j == 0) ? w0 : (j == 1) ? w1 : w2;
    float f[8];
    #pragma unroll
    for (int e = 0; e < 8; ++e) {
      int c = cbase + e;
      float v = wj[o*27 + min(c,2)*9 + min(tap,8)];
      f[e] = (tap <= 8 && c < 3) ? v : 0.f;
    }
    if (t < 960) {
      uint4 wv = { pkh2(f[0],f[1]), pkh2(f[2],f[3]), pkh2(f[4],f[5]), pkh2(f[6],f[7]) };
      wlds[pj*64 + ln] = wv;
    }
  }

  // ---- prefetch tile 0 (x + depth) ----
  int tbase = blockIdx.x * 4;
  float pf[2][3]; float pd[2];
  {
    int tile = tbase;
    int n = tile/196, rem = tile%196, br = rem/14, bc = rem%14;
    int y0 = br*16 - 1, x0 = bc*16 - 1;
    const float* xn = x + (size_t)n*3*HWP;
    const float* dn = depth + (size_t)n*HWP;
    #pragma unroll
    for (int it = 0; it < 2; ++it) {
      int p = min(tid + it*256, 323);
      int yy = y0 + p/18, xx = x0 + p%18;
      int gy = min(max(yy,0),HH-1), gx = min(max(xx,0),HWD-1);
      size_t off = (size_t)gy*HWD + gx;
      pf[it][0] = xn[off]; pf[it][1] = xn[HWP+off]; pf[it][2] = xn[2*HWP+off];
      float dv = dn[off];
      pd[it] = (yy>=0 && yy<HH && xx>=0 && xx<HWD) ? dv : 0.f;  // true 0-pad
    }
  }

  for (int ti = 0; ti < 4; ++ti) {
    int tile = tbase + ti;
    int n = tile/196, rem = tile%196, br = rem/14, bc = rem%14;
    // ---- ds_write current tile (x f16-padded + depth f32) ----
    #pragma unroll
    for (int it = 0; it < 2; ++it) {
      int p = tid + it*256;
      if (p < 324) {
        uint4 v0 = { pkh2(pf[it][0], pf[it][1]), pkh2(pf[it][2], 0.f), 0u, 0u };
        uint4 z  = { 0u, 0u, 0u, 0u };
        *(uint4*)(ts + p*24)      = v0;
        *(uint4*)(ts + p*24 + 8)  = z;
        *(uint4*)(ts + p*24 + 16) = z;
        dt[p] = pd[it];
      }
    }
    // ---- issue next tile's global loads ----
    if (ti < 3) {
      int tile2 = tile + 1;
      int n2 = tile2/196, rem2 = tile2%196, br2 = rem2/14, bc2 = rem2%14;
      int y0 = br2*16 - 1, x0 = bc2*16 - 1;
      const float* xn = x + (size_t)n2*3*HWP;
      const float* dn = depth + (size_t)n2*HWP;
      #pragma unroll
      for (int it = 0; it < 2; ++it) {
        int p = min(tid + it*256, 323);
        int yy = y0 + p/18, xx = x0 + p%18;
        int gy = min(max(yy,0),HH-1), gx = min(max(xx,0),HWD-1);
        size_t off = (size_t)gy*HWD + gx;
        pf[it][0] = xn[off]; pf[it][1] = xn[HWP+off]; pf[it][2] = xn[2*HWP+off];
        float dv = dn[off];
        pd[it] = (yy>=0 && yy<HH && xx>=0 && xx<HWD) ? dv : 0.f;
      }
    }
    __syncthreads();
    // ---- sel bits for this 16x16 tile (math == validated sel_kernel) ----
    {
      int py = tid >> 4, px = tid & 15;
      float c = dt[(py+1)*18 + (px+1)];
      float gr = c / fx;
      float hf = gr * 0.5f;
      uint32_t bits = 0;
      #pragma unroll
      for (int i = 0; i < 3; ++i)
        #pragma unroll
        for (int j = 0; j < 3; ++j) {
          float d = dt[(py+i)*18 + (px+j)];
          int k = i*3 + j;
          uint32_t bb = 0;
          if (fabsf(d - (c + gr)) <= hf) bb |= 1u;
          if (fabsf(d - c) < hf)         bb |= 2u;
          if (fabsf(d - (c - gr)) <= hf) bb |= 4u;
          bits |= bb << (3*k);
        }
      sbits[tid] = bits;
      sel[(size_t)n*HWP + (br*16 + py)*HWD + bc*16 + px] = bits;  // for conv2
    }
    __syncthreads();
    uint32_t svc[4];
    #pragma unroll
    for (int ty = 0; ty < 4; ++ty) svc[ty] = sbits[(wid*4 + ty)*16 + r];
    // ---- MFMA phase ----
    f32x4 acc[4] = {{0,0,0,0},{0,0,0,0},{0,0,0,0},{0,0,0,0}};
    #pragma unroll
    for (int p = 0; p < 5; ++p) {
      int ta = 2*p, tb = (2*p+1 > 8) ? 8 : 2*p+1;   // tap9 dups tap8 (B=0 kills it)
      int dyL = tapPar ? tb/3 : ta/3;
      int dxL = tapPar ? tb%3 : ta%3;
      int shL = 3*(tapPar ? 2*p+1 : 2*p);
      uint4 a[4];
      #pragma unroll
      for (int ty = 0; ty < 4; ++ty) {
        int ly = wid*4 + ty;
        a[ty] = *(const uint4*)(ts + ((ly + dyL)*18 + (r + dxL))*24 + c0);
      }
      #pragma unroll
      for (int j = 0; j < 3; ++j) {
        uint4 bf = wlds[(p*3 + j)*64 + lane];
        #pragma unroll
        for (int ty = 0; ty < 4; ++ty) {
          uint32_t msk = 0u - ((svc[ty] >> (shL + j)) & 1u);
          uint4 am = { a[ty].x & msk, a[ty].y & msk, a[ty].z & msk, a[ty].w & msk };
          acc[ty] = mfma16(am, bf, acc[ty]);
        }
      }
    }
    // ---- epilogue: relu + channel-last f16 store via hbuf bounce ----
    #pragma unroll
    for (int ty = 0; ty < 4; ++ty) {
      int gy = br*16 + wid*4 + ty;
      #pragma unroll
      for (int e = 0; e < 4; ++e) {
        float v = fmaxf(acc[ty][e] + bo, 0.f);
        hbuf[wid*256 + ((lane>>4)*4 + e)*16 + r] = __float2half(v);
      }
      uint2 hw = *(uint2*)&hbuf[wid*256 + lane*4];
      *(uint2*)(h1t + ((size_t)(n*HWP + gy*HWD) + bc*16)*16 + lane*4) = hw;
    }
    __syncthreads();   // ts/dt/sbits/hbuf reads done before next tile's writes
  }
}

// ---------------- conv2: 16->16 via MFMA + ReLU + 2x2 maxpool -> pooled f16 CF ----------------
__global__ __launch_bounds__(256, 4) void conv2_kernel(
    const __half* __restrict__ h1t, const uint32_t* __restrict__ sel,
    const float* __restrict__ w0, const float* __restrict__ w1,
    const float* __restrict__ w2, const float* __restrict__ bias,
    __half* __restrict__ pooled) {
  __shared__ __align__(16) __half ts[324*24];     // 15552 B
  __shared__ __align__(16) uint4 wlds[15*64];     // 15360 B
  __shared__ float pl[64*17];                     //  4352 B
  int tid = threadIdx.x;
  int lane = tid & 63, wid = tid >> 6;
  int r = lane & 15;
  int tapPar = lane >> 5;
  int c0 = ((lane >> 4) & 1) * 8;
  float bo = bias[r];

  // ---- stage B-frags once into LDS ----
  #pragma unroll
  for (int it = 0; it < 4; ++it) {
    int t = tid + it*256;
    int tc = min(t, 959);
    int ln = tc & 63; int pj = tc >> 6;
    int p = pj / 3, j = pj % 3;
    int o = ln & 15; int tap = p*2 + (ln >> 5);
    int cbase = ((ln >> 4) & 1) * 8;
    const float* wj = (j == 0) ? w0 : (j == 1) ? w1 : w2;
    const float* wp = wj + o*144 + cbase*9 + tap;   // [o][c][k]; tap=9 stays in-bounds
    float f[8];
    #pragma unroll
    for (int e = 0; e < 8; ++e) {
      float v = wp[e*9];
      f[e] = (tap <= 8) ? v : 0.f;
    }
    if (t < 960) {
      uint4 wv = { pkh2(f[0],f[1]), pkh2(f[2],f[3]), pkh2(f[4],f[5]), pkh2(f[6],f[7]) };
      wlds[pj*64 + ln] = wv;
    }
  }

  // ---- prefetch tile 0 ----
  int tbase = blockIdx.x * 4;
  uint4 st[3]; uint32_t sv[4];
  {
    int tile = tbase;
    int n = tile/196, rem = tile%196, br = rem/14, bc = rem%14;
    int y0 = br*16 - 1, x0 = bc*16 - 1;
    const __half* hn = h1t + (size_t)n*HWP*16;
    #pragma unroll
    for (int it = 0; it < 3; ++it) {
      int w = min(tid + it*256, 647);
      int p = w >> 1, hh = w & 1;
      int gy = min(max(y0 + p/18, 0), HH-1);
      int gx = min(max(x0 + p%18, 0), HWD-1);
      st[it] = *(const uint4*)(hn + ((size_t)(gy*HWD + gx))*16 + hh*8);
    }
    #pragma unroll
    for (int ty = 0; ty < 4; ++ty)
      sv[ty] = sel[(size_t)n*HWP + (br*16 + wid*4 + ty)*HWD + bc*16 + r];
  }

  for (int ti = 0; ti < 4; ++ti) {
    int tile = tbase + ti;
    int n = tile/196, rem = tile%196, br = rem/14, bc = rem%14;
    // ---- ds_write current tile ----
    #pragma unroll
    for (int it = 0; it < 3; ++it) {
      int w = tid + it*256;
      if (w < 648) {
        int p = w >> 1, hh = w & 1;
        *(uint4*)(ts + p*24 + hh*8) = st[it];
      }
    }
    uint32_t svc[4];
    #pragma unroll
    for (int ty = 0; ty < 4; ++ty) svc[ty] = sv[ty];
    // ---- issue next tile's loads ----
    if (ti < 3) {
      int tile2 = tile + 1;
      int n2 = tile2/196, rem2 = tile2%196, br2 = rem2/14, bc2 = rem2%14;
      int y0 = br2*16 - 1, x0 = bc2*16 - 1;
      const __half* hn = h1t + (size_t)n2*HWP*16;
      #pragma unroll
      for (int it = 0; it < 3; ++it) {
        int w = min(tid + it*256, 647);
        int p = w >> 1, hh = w & 1;
        int gy = min(max(y0 + p/18, 0), HH-1);
        int gx = min(max(x0 + p%18, 0), HWD-1);
        st[it] = *(const uint4*)(hn + ((size_t)(gy*HWD + gx))*16 + hh*8);
      }
      #pragma unroll
      for (int ty = 0; ty < 4; ++ty)
        sv[ty] = sel[(size_t)n2*HWP + (br2*16 + wid*4 + ty)*HWD + bc2*16 + r];
    }
    __syncthreads();
    // ---- MFMA phase ----
    f32x4 acc[4] = {{0,0,0,0},{0,0,0,0},{0,0,0,0},{0,0,0,0}};
    #pragma unroll
    for (int p = 0; p < 5; ++p) {
      int ta = 2*p, tb = (2*p+1 > 8) ? 8 : 2*p+1;
      int dyL = tapPar ? tb/3 : ta/3;
      int dxL = tapPar ? tb%3 : ta%3;
      int shL = 3*(tapPar ? 2*p+1 : 2*p);
      uint4 a[4];
      #pragma unroll
      for (int ty = 0; ty < 4; ++ty) {
        int ly = wid*4 + ty;
        a[ty] = *(const uint4*)(ts + ((ly + dyL)*18 + (r + dxL))*24 + c0);
      }
      #pragma unroll
      for (int j = 0; j < 3; ++j) {
        uint4 bf = wlds[(p*3 + j)*64 + lane];
        #pragma unroll
        for (int ty = 0; ty < 4; ++ty) {
          uint32_t msk = 0u - ((svc[ty] >> (shL + j)) & 1u);
          uint4 am = { a[ty].x & msk, a[ty].y & msk, a[ty].z & msk, a[ty].w & msk };
          acc[ty] = mfma16(am, bf, acc[ty]);
        }
      }
    }
    // ---- relu + 2x2 maxpool -> pl ----
    #pragma unroll
    for (int yp = 0; yp < 2; ++yp) {
      f32x4 v0 = acc[yp*2], v1 = acc[yp*2+1];
      float m00 = fmaxf(fmaxf(v0[0]+bo, 0.f), fmaxf(v0[1]+bo, 0.f));
      float m01 = fmaxf(fmaxf(v0[2]+bo, 0.f), fmaxf(v0[3]+bo, 0.f));
      float m10 = fmaxf(fmaxf(v1[0]+bo, 0.f), fmaxf(v1[1]+bo, 0.f));
      float m11 = fmaxf(fmaxf(v1[2]+bo, 0.f), fmaxf(v1[3]+bo, 0.f));
      int prow = wid*2 + yp;
      int pc0 = (lane >> 4)*2;
      pl[(prow*8 + pc0)*17 + r]     = fmaxf(m00, m10);
      pl[(prow*8 + pc0 + 1)*17 + r] = fmaxf(m01, m11);
    }
    __syncthreads();   // pl ready; also all ts reads done
    for (int t = tid; t < 1024; t += 256) {       // repack channel-first f16
      int oo = t >> 6; int pix = t & 63;
      int pr = pix >> 3, pc = pix & 7;
      pooled[(size_t)(n*16 + oo)*PHW + (br*8 + pr)*PW + bc*8 + pc] =
          __float2half(pl[pix*17 + oo]);
    }
    __syncthreads();   // pl reads done before next tile's writes
  }
}

// ---------------- FC1 via MFMA: 2 otiles (32 outputs) per block ----------------
// XCD swizzle kept (mapping-only); W loads PLAIN (L3-resident across replays).
__global__ __launch_bounds__(256) void fc1_kernel(
    const __half* __restrict__ hin, const float* __restrict__ wgt,
    float* __restrict__ partial) {
  __shared__ __align__(16) uint4 alds[2][256];     //  8 KB
  __shared__ __align__(16) uint4 wlds[2][2][256];  // 16 KB [buf][g][slot]
  __shared__ __align__(16) f32x4 cacc[2][256];     //  8 KB
  int tid = threadIdx.x;
  int b = blockIdx.x;
  int snum = (b & 7)*98 + (b >> 3);   // bijective: 784 = 8 * 98
  int kseg = snum >> 2;
  int grp  = snum & 3;
  int obase = grp * 32;
  int lane = tid & 63, wid = tid >> 6;
  int q8 = tid & 15, row = tid >> 4;              // 16 rows x 16 k-octs
  int sslot = (q8>>2)*64 + (row | ((q8&3) << 4));
  const __half* hp0 = hin + (size_t)row*FCK + kseg*1024 + q8*8;
  const float* wq0  = wgt + (size_t)(obase + row)*FCK + kseg*1024 + q8*8;
  const float* wq1  = wgt + (size_t)(obase + 16 + row)*FCK + kseg*1024 + q8*8;
  uint4 hv; float4 w0a, w0b, w1a, w1b;
  hv  = *(const uint4*)hp0;
  w0a = *(const float4*)wq0; w0b = *(const float4*)(wq0 + 4);
  w1a = *(const float4*)wq1; w1b = *(const float4*)(wq1 + 4);
  f32x4 acc0 = {0,0,0,0}, acc1 = {0,0,0,0};
  for (int ch = 0; ch < 8; ++ch) {
    int buf = ch & 1;
    alds[buf][sslot] = hv;
    wlds[buf][0][sslot] = (uint4){ pkh2(w0a.x,w0a.y), pkh2(w0a.z,w0a.w),
                                   pkh2(w0b.x,w0b.y), pkh2(w0b.z,w0b.w) };
    wlds[buf][1][sslot] = (uint4){ pkh2(w1a.x,w1a.y), pkh2(w1a.z,w1a.w),
                                   pkh2(w1b.x,w1b.y), pkh2(w1b.z,w1b.w) };
    if (ch < 7) {                                  // next chunk's loads pre-barrier
      hv  = *(const uint4*)(hp0 + (ch+1)*128);
      w0a = *(const float4*)(wq0 + (ch+1)*128); w0b = *(const float4*)(wq0 + (ch+1)*128 + 4);
      w1a = *(const float4*)(wq1 + (ch+1)*128); w1b = *(const float4*)(wq1 + (ch+1)*128 + 4);
    }
    __syncthreads();
    uint4 av = alds[buf][wid*64 + lane];
    acc0 = mfma16(av, wlds[buf][0][wid*64 + lane], acc0);
    acc1 = mfma16(av, wlds[buf][1][wid*64 + lane], acc1);
  }
  cacc[0][wid*64 + lane] = acc0;
  cacc[1][wid*64 + lane] = acc1;
  __syncthreads();
  {
    int l = tid & 63, e = tid >> 6;
    int nn = (l >> 4)*4 + e;
    int oo = l & 15;
    #pragma unroll
    for (int g = 0; g < 2; ++g) {
      float s = cacc[g][l][e] + cacc[g][64 + l][e] + cacc[g][128 + l][e] + cacc[g][192 + l][e];
      partial[((size_t)kseg*16 + nn)*128 + obase + g*16 + oo] = s;
    }
  }
}

// ---------------- FC2 (+fused fc1-reduce) + log_softmax, parallelized ----------------
__global__ __launch_bounds__(256) void fc2_kernel(
    const float* __restrict__ partial, const float* __restrict__ fc1b,
    const float* __restrict__ w, const float* __restrict__ b,
    float* __restrict__ out) {
  __shared__ float psum[256];
  __shared__ float row[128];
  __shared__ float v[10];
  __shared__ float lse;
  int n = blockIdx.x, t = threadIdx.x;
  // phase 1: kseg reduce, 2 threads per output (98 ksegs each)
  {
    int o = t & 127, half = t >> 7;
    const float* pp = partial + ((size_t)(half*98)*16 + n)*128 + o;
    float s = 0.f;
    for (int k = 0; k < 98; ++k) s += pp[(size_t)k*2048];
    psum[t] = s;
  }
  __syncthreads();
  if (t < 128) row[t] = fc1b[t] + psum[t] + psum[t + 128];
  __syncthreads();
  // phase 2: 10 dot-products, one per wave-slot, wave-shuffle reduce
  {
    int wv = t >> 6, lane = t & 63;
    for (int d = wv; d < 10; d += 4) {
      float acc = w[d*128 + lane]*row[lane] + w[d*128 + 64 + lane]*row[64 + lane];
      acc += __shfl_xor(acc, 1);  acc += __shfl_xor(acc, 2);
      acc += __shfl_xor(acc, 4);  acc += __shfl_xor(acc, 8);
      acc += __shfl_xor(acc, 16); acc += __shfl_xor(acc, 32);
      if (lane == 0) v[d] = acc + b[d];
    }
  }
  __syncthreads();
  if (t == 0) {
    float m = v[0];
    for (int i = 1; i < 10; ++i) m = fmaxf(m, v[i]);
    float se = 0.f;
    for (int i = 0; i < 10; ++i) se += expf(v[i] - m);
    lse = m + logf(se);
  }
  __syncthreads();
  if (t < 10) out[n*10 + t] = v[t] - lse;
}

extern "C" void kernel_launch(void* const* d_in, const int* in_sizes, int n_in,
                              void* d_out, int out_size, void* d_ws, size_t ws_size,
                              hipStream_t stream) {
  const float* x     = (const float*)d_in[0];
  const float* depth = (const float*)d_in[1];
  const float* fx    = (const float*)d_in[2];
  const float* c1w0  = (const float*)d_in[3];
  const float* c1w1  = (const float*)d_in[4];
  const float* c1w2  = (const float*)d_in[5];
  const float* c1b   = (const float*)d_in[6];
  const float* c2w0  = (const float*)d_in[7];
  const float* c2w1  = (const float*)d_in[8];
  const float* c2w2  = (const float*)d_in[9];
  const float* c2b   = (const float*)d_in[10];
  const float* fc1w  = (const float*)d_in[11];
  const float* fc1b  = (const float*)d_in[12];
  const float* fc2w  = (const float*)d_in[13];
  const float* fc2b  = (const float*)d_in[14];
  float* out = (float*)d_out;

  char* ws = (char*)d_ws;
  uint32_t* sel  = (uint32_t*)ws;                      // 3,211,264 B
  __half* h1t    = (__half*)(ws + 3211264);            // 25,690,112 B
  __half* pooled = (__half*)(ws + 28901376);           //  6,422,528 B
  float* partial = (float*)(ws + 35323904);            //  1,605,632 B

  conv1_kernel<<<784, 256, 0, stream>>>(x, depth, fx, c1w0, c1w1, c1w2, c1b, sel, h1t);
  conv2_kernel<<<784, 256, 0, stream>>>(h1t, sel, c2w0, c2w1, c2w2, c2b, pooled);
  fc1_kernel<<<784, 256, 0, stream>>>(pooled, fc1w, partial);
  fc2_kernel<<<16, 256, 0, stream>>>(partial, fc1b, fc2w, fc2b, out);
}